// Round 5
// baseline (180.957 us; speedup 1.0000x reference)
//
#include <hip/hip_runtime.h>
#include <hip/hip_bf16.h>

// SO3TensorProductLayer: out = relu(128*(x (x) x) @ W1 + b1) @ W2 + b2
// h[c][b] = 128 * sum_{i,j} W1[i*128+j,c] * x[b,i] * x[b,j]
// gemm1 v8: dependency-DAG fix. Evidence: occupancy (v6), FETCH/L2 (v7),
// ring depth, tile shape all changed NOTHING: 32% MfmaUtil invariant,
// ~3250cyc per 32-MFMA step vs 1240cyc matrix demand = in-wave serial
// chain: mfma -> VALU reads mfma result (acc += xi*t) every step.
// v8 moves the xi fold into the B operand: y = bf16(xi*xj) built on VALU
// (v_cvt_pk_bf16_f32, T12 recipe), acc = mfma(A, y, acc) pure C-chain ->
// no MFMA result read until epilogue; B-build for step i+1 independent
// of step i MFMAs -> MFMA/VALU co-issue (m114). Wave c32 x b64 (tn=4)
// so f32 xj fits in 64 VGPR; block c64 x b128; grid 1024 flat, v7-proven
// XCD swizzle (4 A-slices = 2MB/XCD, L2-resident; FETCH 72->24MB held).
// Regs ~190 -> 2 waves/SIMD. Pack/tail/Pb byte-identical.
// REGALLOC (r5/rule20): all arrays statically indexed; A-ring named regs.

typedef __attribute__((ext_vector_type(8))) short short8;   // 8 bf16
typedef __attribute__((ext_vector_type(4))) float floatx4;  // 4 fp32

__device__ __forceinline__ unsigned short f2bf(float f) {
    union { float f; unsigned int u; } v; v.f = f;
    unsigned int r = v.u + 0x7fffu + ((v.u >> 16) & 1u);   // RNE
    return (unsigned short)(r >> 16);
}
__device__ __forceinline__ float bf2f(unsigned short b) {
    union { unsigned int u; float f; } v; v.u = ((unsigned int)b) << 16;
    return v.f;
}

// ---------------------------------------------------------------------------
// Pack W1 [16384 K][512 C] fp32 -> W1Tp chunks of 1KB: chunk(c16,kc) holds
// A-fragment for c rows c16*16..+15, K cols kc*32..+31: wave load at
// (chunkBase + lane*16B) gives lane(m=lane&15,quad=lane>>4) the 8 bf16 of
// W1[K=kc*32+quad*8+j][c=c16*16+m].
__global__ __launch_bounds__(256) void pack_w1_kernel(
    const float* __restrict__ W1, unsigned short* __restrict__ W1Tp) {
    __shared__ float tile[64][65];
    const int k0 = blockIdx.x * 64;
    const int c0 = blockIdx.y * 64;
    const int tr = threadIdx.x >> 4;
    const int tc4 = (threadIdx.x & 15) * 4;
#pragma unroll
    for (int p = 0; p < 4; ++p) {
        int k = p * 16 + tr;
        float4 v = *(const float4*)(W1 + (long)(k0 + k) * 512 + c0 + tc4);
        tile[k][tc4 + 0] = v.x; tile[k][tc4 + 1] = v.y;
        tile[k][tc4 + 2] = v.z; tile[k][tc4 + 3] = v.w;
    }
    __syncthreads();
    const int lane = threadIdx.x & 63;
    const int w = threadIdx.x >> 6;
    const int m = lane & 15, quad = lane >> 4;
#pragma unroll
    for (int pass = 0; pass < 2; ++pass) {
        int chunk = w * 2 + pass;              // 0..7
        int kcL = chunk & 1, c16L = chunk >> 1;
        union { unsigned short s[8]; uint4 u; } o;
#pragma unroll
        for (int j = 0; j < 8; ++j)
            o.s[j] = f2bf(tile[kcL * 32 + quad * 8 + j][c16L * 16 + m]);
        long c16g = (c0 >> 4) + c16L;
        long kcg  = (k0 >> 5) + kcL;
        *(uint4*)(W1Tp + (c16g * 512 + kcg) * 512 + lane * 8) = o.u;
    }
}

// in: [R][C] fp32 -> out: [C][R] bf16 (for W2 -> W2T).
__global__ __launch_bounds__(256) void transpose_cast_kernel(
    const float* __restrict__ in, unsigned short* __restrict__ out, int R, int C) {
    __shared__ float tile[64][65];
    const int r0 = blockIdx.x * 64, c0 = blockIdx.y * 64;
    const int tr = threadIdx.x >> 4;
    const int tc4 = (threadIdx.x & 15) * 4;
#pragma unroll
    for (int p = 0; p < 4; ++p) {
        int r = p * 16 + tr;
        float4 v = *(const float4*)(in + (long)(r0 + r) * C + c0 + tc4);
        tile[r][tc4 + 0] = v.x; tile[r][tc4 + 1] = v.y;
        tile[r][tc4 + 2] = v.z; tile[r][tc4 + 3] = v.w;
    }
    __syncthreads();
#pragma unroll
    for (int p = 0; p < 4; ++p) {
        int c = p * 16 + tr;
        union { unsigned short s[4]; uint2 u; } pk;
#pragma unroll
        for (int e = 0; e < 4; ++e) pk.s[e] = f2bf(tile[tc4 + e][c]);
        *(uint2*)(out + (long)(c0 + c) * R + r0 + tc4) = pk.u;
    }
}

// ---------------------------------------------------------------------------
// gemm1 v8: Pb[z][b][c] (bf16) over i-chunk z. 256 thr = 4 waves (2wm c x
// 2wn b); wave tile c32 x b64 (tm=2, tn=4); block tile c64 x b128.
// Flat grid 1024; XCD swizzle: L=(n&7)*128+(n>>3); bx=L&31 cy=(L>>5)&7
// z=L>>8 -> all bx of one (cy,z) A-slice (512KB) on one XCD, 4/XCD=2MB.

// scaled B fragment: y[e] = bf16(xi * xjF[ks][tn][e]), e=0..7, packed pairs
#define SCALEB(dst, XI, ks, tn)                                            \
    {                                                                      \
        union { unsigned int u[4]; short8 s; } r_;                         \
        _Pragma("unroll")                                                  \
        for (int p_ = 0; p_ < 4; ++p_) {                                   \
            float lo_ = (XI) * xjF[ks][tn][2 * p_];                        \
            float hi_ = (XI) * xjF[ks][tn][2 * p_ + 1];                    \
            asm("v_cvt_pk_bf16_f32 %0, %1, %2"                             \
                : "=v"(r_.u[p_]) : "v"(lo_), "v"(hi_));                    \
        }                                                                  \
        dst = r_.s;                                                        \
    }

#define MM(tm, tn, Aks0, Aks1, B0, B1)                                     \
    acc[tm][tn] = __builtin_amdgcn_mfma_f32_16x16x32_bf16(                 \
        Aks0, B0, acc[tm][tn], 0, 0, 0);                                   \
    acc[tm][tn] = __builtin_amdgcn_mfma_f32_16x16x32_bf16(                 \
        Aks1, B1, acc[tm][tn], 0, 0, 0);

// one i-step: build 8 scaled-B frags, 16 chained MFMAs, prefetch A for I+2
#define A_STEP(Ac00, Ac01, Ac10, Ac11, XI0, XI1, XI2, XI3, I)              \
    {                                                                      \
        short8 Bs00, Bs01, Bs02, Bs03, Bs10, Bs11, Bs12, Bs13;             \
        SCALEB(Bs00, XI0, 0, 0) SCALEB(Bs01, XI1, 0, 1)                    \
        SCALEB(Bs02, XI2, 0, 2) SCALEB(Bs03, XI3, 0, 3)                    \
        SCALEB(Bs10, XI0, 1, 0) SCALEB(Bs11, XI1, 1, 1)                    \
        SCALEB(Bs12, XI2, 1, 2) SCALEB(Bs13, XI3, 1, 3)                    \
        MM(0, 0, Ac00, Ac01, Bs00, Bs10)                                   \
        MM(0, 1, Ac00, Ac01, Bs01, Bs11)                                   \
        MM(0, 2, Ac00, Ac01, Bs02, Bs12)                                   \
        MM(0, 3, Ac00, Ac01, Bs03, Bs13)                                   \
        MM(1, 0, Ac10, Ac11, Bs00, Bs10)                                   \
        MM(1, 1, Ac10, Ac11, Bs01, Bs11)                                   \
        MM(1, 2, Ac10, Ac11, Bs02, Bs12)                                   \
        MM(1, 3, Ac10, Ac11, Bs03, Bs13)                                   \
        const int p_ = ((I) + 2) & 31; /* wrap: tail reload harmless */    \
        Ac00 = *(const short8*)(aB00 + (long)p_ * 2048);                   \
        Ac01 = *(const short8*)(aB01 + (long)p_ * 2048);                   \
        Ac10 = *(const short8*)(aB10 + (long)p_ * 2048);                   \
        Ac11 = *(const short8*)(aB11 + (long)p_ * 2048);                   \
    }

__global__ __launch_bounds__(256, 2) void gemm1_kernel(
    const float* __restrict__ x,               // [4096][128]
    const unsigned short* __restrict__ W1Tp,
    unsigned short* __restrict__ Pb) {         // [4][4096][512] bf16
    __shared__ float xT[128][34];              // [b_local][i_local]; even stride for b64 reads
    const int tid = threadIdx.x;
    // XCD-locality swizzle (bijective, 1024 blocks, 8 XCDs)
    const int n = blockIdx.x;
    const int L = (n & 7) * 128 + (n >> 3);
    const int b0 = (L & 31) * 128;
    const int c0 = ((L >> 5) & 7) * 64;
    const int zi = L >> 8;
    const int i0 = zi * 32;

    // stage xT[b][i], coalesced global reads
    for (int idx = tid; idx < 128 * 32; idx += 256) {
        int bL = idx >> 5, iL = idx & 31;
        xT[bL][iL] = x[(long)(b0 + bL) * 128 + i0 + iL];
    }
    __syncthreads();

    const int wid = tid >> 6;
    const int wm = wid >> 1, wn = wid & 1;
    const int lane = tid & 63;
    const int n16 = lane & 15, quad = lane >> 4;
    const int bBase = b0 + wn * 64;
    const int c16base = (c0 >> 4) + wm * 2;
    const int xrow0 = wn * 64 + n16;           // xT rows for tn=0..3
    const int xrow1 = xrow0 + 16;
    const int xrow2 = xrow0 + 32;
    const int xrow3 = xrow0 + 48;

    floatx4 acc[2][4];
#pragma unroll
    for (int tm = 0; tm < 2; ++tm)
#pragma unroll
        for (int tn = 0; tn < 4; ++tn) acc[tm][tn] = (floatx4){0.f, 0.f, 0.f, 0.f};

#pragma unroll
    for (int jh = 0; jh < 2; ++jh) {
        // x j-fragments kept in f32 (64 VGPRs), statically indexed
        float xjF[2][4][8];
#pragma unroll
        for (int ks = 0; ks < 2; ++ks)
#pragma unroll
            for (int tn = 0; tn < 4; ++tn) {
                const float* xp = x + (long)(bBase + tn * 16 + n16) * 128
                                    + jh * 64 + ks * 32 + quad * 8;
                float4 v0 = *(const float4*)xp;
                float4 v1 = *(const float4*)(xp + 4);
                xjF[ks][tn][0] = v0.x; xjF[ks][tn][1] = v0.y;
                xjF[ks][tn][2] = v0.z; xjF[ks][tn][3] = v0.w;
                xjF[ks][tn][4] = v1.x; xjF[ks][tn][5] = v1.y;
                xjF[ks][tn][6] = v1.z; xjF[ks][tn][7] = v1.w;
            }
        // A chunk base pointers (scalarized); per-i advance = 2048 u16
        const unsigned short* aB00 = W1Tp
            + ((long)(c16base + 0) * 512 + (long)i0 * 4 + jh * 2 + 0) * 512
            + lane * 8;
        const unsigned short* aB01 = aB00 + 512;
        const unsigned short* aB10 = W1Tp
            + ((long)(c16base + 1) * 512 + (long)i0 * 4 + jh * 2 + 0) * 512
            + lane * 8;
        const unsigned short* aB11 = aB10 + 512;

        // depth-2 ring, fully scalarized (8 named short8)
        short8 A0_00 = *(const short8*)(aB00);
        short8 A0_01 = *(const short8*)(aB01);
        short8 A0_10 = *(const short8*)(aB10);
        short8 A0_11 = *(const short8*)(aB11);
        short8 A1_00 = *(const short8*)(aB00 + 2048);
        short8 A1_01 = *(const short8*)(aB01 + 2048);
        short8 A1_10 = *(const short8*)(aB10 + 2048);
        short8 A1_11 = *(const short8*)(aB11 + 2048);

#pragma unroll 1
        for (int ib = 0; ib < 16; ++ib) {
            const int i = ib * 2;
            // xi for both steps of this body (b64 pair reads, stride 34 even)
            float2 xi0p = *(const float2*)&xT[xrow0][i];
            float2 xi1p = *(const float2*)&xT[xrow1][i];
            float2 xi2p = *(const float2*)&xT[xrow2][i];
            float2 xi3p = *(const float2*)&xT[xrow3][i];
            A_STEP(A0_00, A0_01, A0_10, A0_11,
                   xi0p.x, xi1p.x, xi2p.x, xi3p.x, i)
            A_STEP(A1_00, A1_01, A1_10, A1_11,
                   xi0p.y, xi1p.y, xi2p.y, xi3p.y, i + 1)
        }
    }

    // store bf16 partial in [z][b][c]: per (tm,tn) lane owns 4 c-consecutive
    unsigned short* pb = Pb + (long)zi * (4096L * 512);
#pragma unroll
    for (int tm = 0; tm < 2; ++tm)
#pragma unroll
        for (int tn = 0; tn < 4; ++tn) {
            int b = bBase + tn * 16 + n16;
            int cb = (c16base + tm) * 16 + quad * 4;
            union { unsigned short s[4]; uint2 u; } pk;
#pragma unroll
            for (int r = 0; r < 4; ++r) pk.s[r] = f2bf(acc[tm][tn][r]);
            *(uint2*)(pb + (long)b * 512 + cb) = pk.u;
        }
}

// ---------------------------------------------------------------------------
// tail: h[b][c] = relu(128*sum_z Pb[z][b][c] + b1[c]) (bf16, LDS), then
// out[b][o] = h @ W2T + b2. 256 thr = 4 waves; b-tile 16 (grid 256 blocks);
// each wave owns 64 o columns.
__global__ __launch_bounds__(256) void tail_kernel(
    const unsigned short* __restrict__ Pb,     // [4][4096][512] bf16
    const float* __restrict__ b1,              // [512]
    const unsigned short* __restrict__ W2T,    // [256][512] bf16
    const float* __restrict__ b2,              // [256]
    float* __restrict__ out) {                 // [4096][256]
    __shared__ unsigned short hL[16][516];
    __shared__ float b1s[512];
    const int tid = threadIdx.x;
    const int b0 = blockIdx.x * 16;
    b1s[tid] = b1[tid];
    b1s[tid + 256] = b1[tid + 256];
    __syncthreads();

    const unsigned int* Pu = (const unsigned int*)Pb;   // 2 bf16 per uint
#pragma unroll 4
    for (int idx = tid; idx < 16 * 256; idx += 256) {
        int bL = idx >> 8;                      // 0..15
        int cu = idx & 255;                     // uint index; c = 2*cu
        float s0 = 0.f, s1 = 0.f;
#pragma unroll
        for (int z = 0; z < 4; ++z) {
            unsigned int u = Pu[((long)z * 4096 + b0 + bL) * 256 + cu];
            s0 += bf2f((unsigned short)(u & 0xffff));
            s1 += bf2f((unsigned short)(u >> 16));
        }
        int c = cu * 2;
        float v0 = fmaxf(fmaf(128.f, s0, b1s[c]), 0.f);
        float v1 = fmaxf(fmaf(128.f, s1, b1s[c + 1]), 0.f);
        unsigned int pk = (unsigned int)f2bf(v0) | ((unsigned int)f2bf(v1) << 16);
        *(unsigned int*)&hL[bL][c] = pk;
    }
    __syncthreads();

    const int w = tid >> 6, lane = tid & 63;
    const int n16 = lane & 15, quad = lane >> 4;
    const int o0 = w * 64;
    floatx4 acc[4];
#pragma unroll
    for (int tn = 0; tn < 4; ++tn) acc[tn] = (floatx4){0.f, 0.f, 0.f, 0.f};

#pragma unroll 4
    for (int ks = 0; ks < 16; ++ks) {
        short8 Af, Bf[4];
        {
            const unsigned short* p = &hL[n16][ks * 32 + quad * 8];
            union { uint2 u[2]; short8 s; } cvt;
            cvt.u[0] = *(const uint2*)p;
            cvt.u[1] = *(const uint2*)(p + 4);
            Af = cvt.s;
        }
#pragma unroll
        for (int tn = 0; tn < 4; ++tn)
            Bf[tn] = *(const short8*)(W2T + (long)(o0 + tn * 16 + n16) * 512
                                      + ks * 32 + quad * 8);
#pragma unroll
        for (int tn = 0; tn < 4; ++tn)
            acc[tn] = __builtin_amdgcn_mfma_f32_16x16x32_bf16(
                Af, Bf[tn], acc[tn], 0, 0, 0);
    }
#pragma unroll
    for (int tn = 0; tn < 4; ++tn) {
        float bias = b2[o0 + tn * 16 + n16];
#pragma unroll
        for (int r = 0; r < 4; ++r)
            out[(long)(b0 + quad * 4 + r) * 256
                + o0 + tn * 16 + n16] = acc[tn][r] + bias;
    }
}

extern "C" void kernel_launch(void* const* d_in, const int* in_sizes, int n_in,
                              void* d_out, int out_size, void* d_ws, size_t ws_size,
                              hipStream_t stream) {
    const float* x  = (const float*)d_in[0];   // [4096,128]
    const float* W1 = (const float*)d_in[1];   // [16384,512]
    const float* b1 = (const float*)d_in[2];   // [512]
    const float* W2 = (const float*)d_in[3];   // [512,256]
    const float* b2 = (const float*)d_in[4];   // [256]
    float* out = (float*)d_out;                // [4096,256]

    char* ws = (char*)d_ws;
    unsigned short* W1Tp = (unsigned short*)(ws);                 // 16.78 MB
    unsigned short* W2T  = (unsigned short*)(ws + 16777216);      // 0.26 MB
    unsigned short* Pb   = (unsigned short*)(ws + 16777216 + 262144); // 16.78 MB bf16

    pack_w1_kernel<<<dim3(256, 8), 256, 0, stream>>>(W1, W1Tp);
    transpose_cast_kernel<<<dim3(8, 4), 256, 0, stream>>>(W2, W2T, 512, 256);
    gemm1_kernel<<<dim3(1024), 256, 0, stream>>>(x, W1Tp, Pb);
    tail_kernel<<<dim3(256), 256, 0, stream>>>(Pb, b1, W2T, b2, out);
}

// Round 6
// 170.303 us; speedup vs baseline: 1.0626x; 1.0626x over previous
//
#include <hip/hip_runtime.h>
#include <hip/hip_bf16.h>

// SO3TensorProductLayer: out = relu(128*(x (x) x) @ W1 + b1) @ W2 + b2
// h[c][b] = 128 * sum_i x[b,i] * (sum_j W1T[c][i*128+j] * x[b,j])
// v9: pipeline cleanup. gemm1 hot loop = v7 byte-identical (passed,
// 86.5us, MfmaUtil 32% plateau — structural, deferred). Changes:
//  (1) Pb fragment-packed: wave stores each 16b x 16c acc tile as one
//      contiguous 512B record (lane*8B) -> coalesced; v7 measured 1.9x
//      write amplification (31.7MB for 16.8MB Pb) from 1KB-strided lanes.
//  (2) prep = pack_w1 + transpose_cast merged (flat grid 2080) -> one
//      fewer launch. Non-gemm1 time is ~89us constant, never profiled.
//  (3) tail z-reduction consumes fragments coalesced, in-register;
//      arithmetic bit-identical to old tail (same sum order/f2bf/relu).
// REGALLOC (r5/rule20): no runtime-indexed vector arrays anywhere.

typedef __attribute__((ext_vector_type(8))) short short8;   // 8 bf16
typedef __attribute__((ext_vector_type(4))) float floatx4;  // 4 fp32

__device__ __forceinline__ unsigned short f2bf(float f) {
    union { float f; unsigned int u; } v; v.f = f;
    unsigned int r = v.u + 0x7fffu + ((v.u >> 16) & 1u);   // RNE
    return (unsigned short)(r >> 16);
}
__device__ __forceinline__ float bf2f(unsigned short b) {
    union { unsigned int u; float f; } v; v.u = ((unsigned int)b) << 16;
    return v.f;
}

// ---------------------------------------------------------------------------
// prep: blocks 0..2047 pack W1 -> W1Tp (MFMA A-fragment chunks of 1KB);
// blocks 2048..2079 transpose W2 [512][256] f32 -> W2T [256][512] bf16.
// W1Tp chunk(c16,kc): wave load at (chunkBase + lane*16B) gives lane
// (m=lane&15,quad=lane>>4) the 8 bf16 of W1[K=kc*32+quad*8+j][c=c16*16+m].
__global__ __launch_bounds__(256) void prep_kernel(
    const float* __restrict__ W1, unsigned short* __restrict__ W1Tp,
    const float* __restrict__ W2, unsigned short* __restrict__ W2T) {
    __shared__ float tile[64][65];
    const int blk = blockIdx.x;
    const int tr = threadIdx.x >> 4;
    const int tc4 = (threadIdx.x & 15) * 4;
    if (blk < 2048) {
        const int k0 = (blk & 255) * 64;
        const int c0 = (blk >> 8) * 64;
#pragma unroll
        for (int p = 0; p < 4; ++p) {
            int k = p * 16 + tr;
            float4 v = *(const float4*)(W1 + (long)(k0 + k) * 512 + c0 + tc4);
            tile[k][tc4 + 0] = v.x; tile[k][tc4 + 1] = v.y;
            tile[k][tc4 + 2] = v.z; tile[k][tc4 + 3] = v.w;
        }
        __syncthreads();
        const int lane = threadIdx.x & 63;
        const int w = threadIdx.x >> 6;
        const int m = lane & 15, quad = lane >> 4;
#pragma unroll
        for (int pass = 0; pass < 2; ++pass) {
            int chunk = w * 2 + pass;              // 0..7
            int kcL = chunk & 1, c16L = chunk >> 1;
            union { unsigned short s[8]; uint4 u; } o;
#pragma unroll
            for (int j = 0; j < 8; ++j)
                o.s[j] = f2bf(tile[kcL * 32 + quad * 8 + j][c16L * 16 + m]);
            long c16g = (c0 >> 4) + c16L;
            long kcg  = (k0 >> 5) + kcL;
            *(uint4*)(W1Tp + (c16g * 512 + kcg) * 512 + lane * 8) = o.u;
        }
    } else {
        const int t = blk - 2048;                  // 0..31
        const int r0 = (t & 7) * 64, c0 = (t >> 3) * 64;
        const int R = 512, C = 256;
#pragma unroll
        for (int p = 0; p < 4; ++p) {
            int r = p * 16 + tr;
            float4 v = *(const float4*)(W2 + (long)(r0 + r) * C + c0 + tc4);
            tile[r][tc4 + 0] = v.x; tile[r][tc4 + 1] = v.y;
            tile[r][tc4 + 2] = v.z; tile[r][tc4 + 3] = v.w;
        }
        __syncthreads();
#pragma unroll
        for (int p = 0; p < 4; ++p) {
            int c = p * 16 + tr;
            union { unsigned short s[4]; uint2 u; } pk;
#pragma unroll
            for (int e = 0; e < 4; ++e) pk.s[e] = f2bf(tile[tc4 + e][c]);
            *(uint2*)(W2T + (long)(c0 + c) * R + r0 + tc4) = pk.u;
        }
    }
}

// ---------------------------------------------------------------------------
// gemm1 (v7 hot loop): Pb fragment-packed over i-chunk z. 256 thr = 4 waves
// (2wm c x 2wn b); wave tile c32 x b128 (tm=2, tn=8); block c64 x b256.
// Flat grid 512; XCD swizzle: L=(n&7)*64+(n>>3); bx=L&15 cy=(L>>4)&7
// z=L>>7 -> all bx of one (cy,z) A-slice on one XCD (2MB/XCD, L2-resident).
// Pb record (z,ct,bt): 64 lanes x uint2 = 512B; lane holds acc rows
// c=ct*16+quad*4+r for b=bt*16+n16.

#define A_STEP(Ac00, Ac01, Ac10, Ac11, I)                                  \
    {                                                                      \
        float xi[8];                                                       \
        _Pragma("unroll")                                                  \
        for (int tn = 0; tn < 8; ++tn)                                     \
            xi[tn] = xT[bLloc + tn * 16][(I)];                             \
        _Pragma("unroll")                                                  \
        for (int tn = 0; tn < 8; ++tn) {                                   \
            floatx4 t0 = __builtin_amdgcn_mfma_f32_16x16x32_bf16(          \
                Ac00, Xf[0][tn], zero4, 0, 0, 0);                          \
            t0 = __builtin_amdgcn_mfma_f32_16x16x32_bf16(                  \
                Ac01, Xf[1][tn], t0, 0, 0, 0);                             \
            acc[0][tn] += xi[tn] * t0;                                     \
            floatx4 t1 = __builtin_amdgcn_mfma_f32_16x16x32_bf16(          \
                Ac10, Xf[0][tn], zero4, 0, 0, 0);                          \
            t1 = __builtin_amdgcn_mfma_f32_16x16x32_bf16(                  \
                Ac11, Xf[1][tn], t1, 0, 0, 0);                             \
            acc[1][tn] += xi[tn] * t1;                                     \
        }                                                                  \
        const int p_ = ((I) + 4) & 31; /* wrap: tail reload is harmless */ \
        Ac00 = *(const short8*)(aB00 + (long)p_ * 2048);                   \
        Ac01 = *(const short8*)(aB01 + (long)p_ * 2048);                   \
        Ac10 = *(const short8*)(aB10 + (long)p_ * 2048);                   \
        Ac11 = *(const short8*)(aB11 + (long)p_ * 2048);                   \
    }

__global__ __launch_bounds__(256, 2) void gemm1_kernel(
    const float* __restrict__ x,               // [4096][128]
    const unsigned short* __restrict__ W1Tp,
    unsigned short* __restrict__ Pb) {         // fragment-packed partials
    __shared__ float xT[256][34];              // [b_local][i_local]
    const int tid = threadIdx.x;
    // XCD-locality swizzle (bijective, 512 blocks, 8 XCDs)
    const int n = blockIdx.x;
    const int L = (n & 7) * 64 + (n >> 3);
    const int b0 = (L & 15) * 256;
    const int c0 = ((L >> 4) & 7) * 64;
    const int zi = L >> 7;
    const int i0 = zi * 32;

    // stage xT[b][i], coalesced global reads
    for (int idx = tid; idx < 256 * 32; idx += 256) {
        int bL = idx >> 5, iL = idx & 31;
        xT[bL][iL] = x[(long)(b0 + bL) * 128 + i0 + iL];
    }
    __syncthreads();

    const int wid = tid >> 6;
    const int wm = wid >> 1, wn = wid & 1;
    const int lane = tid & 63;
    const int n16 = lane & 15, quad = lane >> 4;
    const int bBase = b0 + wn * 128;
    const int c16base = (c0 >> 4) + wm * 2;
    const int bLloc = wn * 128 + n16;          // xT row for tn=0

    floatx4 acc[2][8];
#pragma unroll
    for (int tm = 0; tm < 2; ++tm)
#pragma unroll
        for (int tn = 0; tn < 8; ++tn) acc[tm][tn] = (floatx4){0.f, 0.f, 0.f, 0.f};
    const floatx4 zero4 = (floatx4){0.f, 0.f, 0.f, 0.f};

#pragma unroll
    for (int jh = 0; jh < 2; ++jh) {
        // x B-fragments, register-resident for this j-half (64 VGPRs)
        short8 Xf[2][8];
#pragma unroll
        for (int ks = 0; ks < 2; ++ks)
#pragma unroll
            for (int tn = 0; tn < 8; ++tn) {
                const float* xp = x + (long)(bBase + tn * 16 + n16) * 128
                                    + jh * 64 + ks * 32 + quad * 8;
                float4 v0 = *(const float4*)xp;
                float4 v1 = *(const float4*)(xp + 4);
                short8 f;
                f[0] = (short)f2bf(v0.x); f[1] = (short)f2bf(v0.y);
                f[2] = (short)f2bf(v0.z); f[3] = (short)f2bf(v0.w);
                f[4] = (short)f2bf(v1.x); f[5] = (short)f2bf(v1.y);
                f[6] = (short)f2bf(v1.z); f[7] = (short)f2bf(v1.w);
                Xf[ks][tn] = f;
            }
        // A chunk base pointers (scalarized); per-i advance = 2048 u16
        const unsigned short* aB00 = W1Tp
            + ((long)(c16base + 0) * 512 + (long)i0 * 4 + jh * 2 + 0) * 512
            + lane * 8;
        const unsigned short* aB01 = aB00 + 512;
        const unsigned short* aB10 = W1Tp
            + ((long)(c16base + 1) * 512 + (long)i0 * 4 + jh * 2 + 0) * 512
            + lane * 8;
        const unsigned short* aB11 = aB10 + 512;

        // depth-4 ring, fully scalarized (16 named short8)
        short8 A0_00 = *(const short8*)(aB00);
        short8 A0_01 = *(const short8*)(aB01);
        short8 A0_10 = *(const short8*)(aB10);
        short8 A0_11 = *(const short8*)(aB11);
        short8 A1_00 = *(const short8*)(aB00 + 1 * 2048);
        short8 A1_01 = *(const short8*)(aB01 + 1 * 2048);
        short8 A1_10 = *(const short8*)(aB10 + 1 * 2048);
        short8 A1_11 = *(const short8*)(aB11 + 1 * 2048);
        short8 A2_00 = *(const short8*)(aB00 + 2 * 2048);
        short8 A2_01 = *(const short8*)(aB01 + 2 * 2048);
        short8 A2_10 = *(const short8*)(aB10 + 2 * 2048);
        short8 A2_11 = *(const short8*)(aB11 + 2 * 2048);
        short8 A3_00 = *(const short8*)(aB00 + 3 * 2048);
        short8 A3_01 = *(const short8*)(aB01 + 3 * 2048);
        short8 A3_10 = *(const short8*)(aB10 + 3 * 2048);
        short8 A3_11 = *(const short8*)(aB11 + 3 * 2048);

#pragma unroll 1
        for (int ib = 0; ib < 8; ++ib) {
            const int i = ib * 4;
            A_STEP(A0_00, A0_01, A0_10, A0_11, i + 0)
            A_STEP(A1_00, A1_01, A1_10, A1_11, i + 1)
            A_STEP(A2_00, A2_01, A2_10, A2_11, i + 2)
            A_STEP(A3_00, A3_01, A3_10, A3_11, i + 3)
        }
    }

    // store bf16 partials, fragment-packed: record (zi,ct,bt) = 512B,
    // lane writes uint2 at lane*8B -> fully coalesced.
#pragma unroll
    for (int tm = 0; tm < 2; ++tm)
#pragma unroll
        for (int tn = 0; tn < 8; ++tn) {
            int ct = c16base + tm;                 // 0..31
            int bt = (bBase >> 4) + tn;            // 0..255
            union { unsigned short s[4]; uint2 u; } pk;
#pragma unroll
            for (int r = 0; r < 4; ++r) pk.s[r] = f2bf(acc[tm][tn][r]);
            *(uint2*)(Pb + (((long)(zi * 32 + ct) * 256 + bt) * 64 + lane) * 4)
                = pk.u;
        }
}

// ---------------------------------------------------------------------------
// tail: z-reduce fragment-packed Pb in-register, h = relu(128*sum + b1)
// -> hL[b][c] (bf16, LDS), then out[b][o] = h @ W2T + b2. 256 thr = 4
// waves; one b16-tile per block (grid 256); wave w reduces ct = 4*cc+w.
__global__ __launch_bounds__(256) void tail_kernel(
    const unsigned short* __restrict__ Pb,     // fragment-packed partials
    const float* __restrict__ b1,              // [512]
    const unsigned short* __restrict__ W2T,    // [256][512] bf16
    const float* __restrict__ b2,              // [256]
    float* __restrict__ out) {                 // [4096][256]
    __shared__ unsigned short hL[16][516];
    __shared__ float b1s[512];
    const int tid = threadIdx.x;
    const int bt = blockIdx.x;                 // b0 = bt*16
    b1s[tid] = b1[tid];
    b1s[tid + 256] = b1[tid + 256];
    __syncthreads();

    const int w = tid >> 6, lane = tid & 63;
    const int n16 = lane & 15, quad = lane >> 4;

#pragma unroll
    for (int cc = 0; cc < 8; ++cc) {
        const int ct = cc * 4 + w;             // 0..31, wave-partitioned
        float s0 = 0.f, s1 = 0.f, s2 = 0.f, s3 = 0.f;
#pragma unroll
        for (int z = 0; z < 4; ++z) {
            uint2 u = *(const uint2*)(Pb
                + (((long)(z * 32 + ct) * 256 + bt) * 64 + lane) * 4);
            s0 += bf2f((unsigned short)(u.x & 0xffff));
            s1 += bf2f((unsigned short)(u.x >> 16));
            s2 += bf2f((unsigned short)(u.y & 0xffff));
            s3 += bf2f((unsigned short)(u.y >> 16));
        }
        const int c = ct * 16 + quad * 4;
        float v0 = fmaxf(fmaf(128.f, s0, b1s[c + 0]), 0.f);
        float v1 = fmaxf(fmaf(128.f, s1, b1s[c + 1]), 0.f);
        float v2 = fmaxf(fmaf(128.f, s2, b1s[c + 2]), 0.f);
        float v3 = fmaxf(fmaf(128.f, s3, b1s[c + 3]), 0.f);
        union { unsigned short s[4]; uint2 u; } pk;
        pk.s[0] = f2bf(v0); pk.s[1] = f2bf(v1);
        pk.s[2] = f2bf(v2); pk.s[3] = f2bf(v3);
        *(uint2*)&hL[n16][c] = pk.u;
    }
    __syncthreads();

    const int o0 = w * 64;
    floatx4 acc[4];
#pragma unroll
    for (int tn = 0; tn < 4; ++tn) acc[tn] = (floatx4){0.f, 0.f, 0.f, 0.f};

#pragma unroll 4
    for (int ks = 0; ks < 16; ++ks) {
        short8 Af, Bf[4];
        {
            const unsigned short* p = &hL[n16][ks * 32 + quad * 8];
            union { uint2 u[2]; short8 s; } cvt;
            cvt.u[0] = *(const uint2*)p;
            cvt.u[1] = *(const uint2*)(p + 4);
            Af = cvt.s;
        }
#pragma unroll
        for (int tn = 0; tn < 4; ++tn)
            Bf[tn] = *(const short8*)(W2T + (long)(o0 + tn * 16 + n16) * 512
                                      + ks * 32 + quad * 8);
#pragma unroll
        for (int tn = 0; tn < 4; ++tn)
            acc[tn] = __builtin_amdgcn_mfma_f32_16x16x32_bf16(
                Af, Bf[tn], acc[tn], 0, 0, 0);
    }
#pragma unroll
    for (int tn = 0; tn < 4; ++tn) {
        float bias = b2[o0 + tn * 16 + n16];
#pragma unroll
        for (int r = 0; r < 4; ++r)
            out[(long)(bt * 16 + quad * 4 + r) * 256
                + o0 + tn * 16 + n16] = acc[tn][r] + bias;
    }
}

extern "C" void kernel_launch(void* const* d_in, const int* in_sizes, int n_in,
                              void* d_out, int out_size, void* d_ws, size_t ws_size,
                              hipStream_t stream) {
    const float* x  = (const float*)d_in[0];   // [4096,128]
    const float* W1 = (const float*)d_in[1];   // [16384,512]
    const float* b1 = (const float*)d_in[2];   // [512]
    const float* W2 = (const float*)d_in[3];   // [512,256]
    const float* b2 = (const float*)d_in[4];   // [256]
    float* out = (float*)d_out;                // [4096,256]

    char* ws = (char*)d_ws;
    unsigned short* W1Tp = (unsigned short*)(ws);                 // 16.78 MB
    unsigned short* W2T  = (unsigned short*)(ws + 16777216);      // 0.26 MB
    unsigned short* Pb   = (unsigned short*)(ws + 16777216 + 262144); // 16.78 MB bf16

    prep_kernel<<<dim3(2080), 256, 0, stream>>>(W1, W1Tp, W2, W2T);
    gemm1_kernel<<<dim3(512), 256, 0, stream>>>(x, W1Tp, Pb);
    tail_kernel<<<dim3(256), 256, 0, stream>>>(Pb, b1, W2T, b2, out);
}